// Round 7
// baseline (451.366 us; speedup 1.0000x reference)
//
#include <hip/hip_runtime.h>
#include <math.h>

#define NTYPE   4
#define NWAVE   8
#define NORBIT  128
#define NB      32
#define NATOM   256
#define NPP     (NATOM * 64)      /* 16384 pairs per batch */
#define NPAIR   (NB * NPP)        /* 524288 */
#define TOTATOM (NB * NATOM)      /* 8192  */
#define NPARA   13                /* 1 + 3 + 9 */

__device__ __forceinline__ float fast_tanh(float x) {
    float ax = fabsf(x);
    float e  = __expf(-2.0f * ax);
    float r  = (1.0f - e) / (1.0f + e);
    return copysignf(r, x);
}

// One block per batch: LDS sort + 3 fused density passes (coeff in LDS).
__global__ __launch_bounds__(1024, 1) void k_all(
    const int* __restrict__ atom_index, const float* __restrict__ cart,
    const float* __restrict__ shifts, const int* __restrict__ species,
    const float* __restrict__ params, const float* __restrict__ rs,
    const float* __restrict__ inta, const float* __restrict__ hyper,
    const float* __restrict__ W0g, const float* __restrict__ E0,
    const float* __restrict__ W1g, const float* __restrict__ E1,
    float4* __restrict__ rec, float* __restrict__ out)
{
    const int b = blockIdx.x, t = threadIdx.x;
    const int wave = t >> 6, lane = t & 63;
    const int pl = lane >> 3, w = lane & 7;

    __shared__ float cA[NATOM * NWAVE];          // 8 KB  coeff ping
    __shared__ float cB[NATOM * NWAVE];          // 8 KB  coeff pong
    __shared__ float sHyp[3 * NWAVE * NORBIT];   // 12 KB
    __shared__ float sW0[NORBIT * NWAVE];        // 4 KB
    __shared__ float sW1[NORBIT * NWAVE];        // 4 KB
    __shared__ float stash[16][NWAVE * 16];      // 8 KB  per-wave S stash
    __shared__ int   hist[NATOM], cur[NATOM], loffs[NATOM + 1];
    __shared__ float cx[NATOM], cy[NATOM], cz[NATOM];
    __shared__ int   spl[NATOM];

    // ---- phase 0: independent LDS fills ----
    if (t < NATOM) {
        hist[t] = 0;
        int ag = b * NATOM + t;
        cx[t] = cart[ag * 3 + 0];
        cy[t] = cart[ag * 3 + 1];
        cz[t] = cart[ag * 3 + 2];
        spl[t] = species[ag];
    }
    for (int e = t; e < 3 * NWAVE * NORBIT; e += 1024) sHyp[e] = hyper[e];
    for (int e = t; e < NORBIT * NWAVE; e += 1024) { sW0[e] = W0g[e]; sW1[e] = W1g[e]; }
    __syncthreads();

    // ---- phase 1: coeff init + histogram ----
    for (int e = t; e < NATOM * NWAVE; e += 1024)
        cA[e] = params[spl[e >> 3] * NWAVE + (e & 7)];
    int iloc[16];
    const int base = b * NPP;
#pragma unroll
    for (int k = 0; k < 16; k++) {
        iloc[k] = atom_index[base + t + k * 1024];
        atomicAdd(&hist[iloc[k]], 1);
    }
    __syncthreads();

    // ---- phase 2: exclusive scan over 256 bins ----
    if (t < NATOM) cur[t] = hist[t];
    __syncthreads();
    for (int d = 1; d < NATOM; d <<= 1) {
        int v = 0;
        if (t < NATOM && t >= d) v = cur[t - d];
        __syncthreads();
        if (t < NATOM) cur[t] += v;
        __syncthreads();
    }
    if (t < NATOM) {
        int ex = cur[t] - hist[t];
        loffs[t] = ex;
        cur[t] = ex;
    }
    if (t == 0) loffs[NATOM] = NPP;
    __syncthreads();

    // ---- phase 3: scatter packed records into this batch's rec slab ----
#pragma unroll
    for (int k = 0; k < 16; k++) {
        int p = t + k * 1024;
        int i = iloc[k];
        int j = atom_index[NPAIR + base + p];
        float dx = cx[i] - cx[j] + shifts[(base + p) * 3 + 0];
        float dy = cy[i] - cy[j] + shifts[(base + p) * 3 + 1];
        float dz = cz[i] - cz[j] + shifts[(base + p) * 3 + 2];
        int pos = atomicAdd(&cur[i], 1);
        rec[base + pos] = make_float4(dx, dy, dz, __int_as_float(j | (spl[j] << 16)));
    }
    __syncthreads();      // drains vmem stores; rec now readable (same XCD L2)

    // ---- per-lane radial tables ----
    float rs0 = rs[w],   rs1 = rs[8 + w],   rs2 = rs[16 + w],   rs3 = rs[24 + w];
    float in0 = inta[w], in1 = inta[8 + w], in2 = inta[16 + w], in3 = inta[24 + w];

    // ---- one density pass over this batch's 256 atoms ----
    auto pass = [&](const float* cin, float* cout, const float* sW,
                    const float* Eg, int mode) {
        for (int ai = wave; ai < NATOM; ai += 16) {
            const int start = loffs[ai];
            const int n = loffs[ai + 1] - start;
            const float4* ra = rec + base + start;

            float S[NPARA];
#pragma unroll
            for (int k = 0; k < NPARA; k++) S[k] = 0.0f;

            int idx = pl;
            float4 r = ra[idx];                       // safe preload (in ws)
            while (idx < n) {
                float4 rn = ra[idx + 8];              // prefetch (in ws)
                int jp = __float_as_int(r.w);
                int j  = jp & 0xFFFF;
                int sp = jp >> 16;
                float cj = cin[j * NWAVE + w];        // LDS gather
                float d  = sqrtf(r.x * r.x + r.y * r.y + r.z * r.z);
                float co = __cosf(d * 0.62831853071795864769f);   // pi/CUTOFF
                float fc = 0.5f * co + 0.5f;
                fc = fc * fc;
                float rw = (sp == 0) ? rs0 : (sp == 1) ? rs1 : (sp == 2) ? rs2 : rs3;
                float iw = (sp == 0) ? in0 : (sp == 1) ? in1 : (sp == 2) ? in2 : in3;
                float dr = d - rw;
                float q  = fc * __expf(iw * dr * dr) * cj;
                S[0] += q;
                float qx = q * r.x, qy = q * r.y, qz = q * r.z;
                S[1] += qx; S[2] += qy; S[3] += qz;
                S[4]  += qx * r.x; S[5]  += qx * r.y; S[6]  += qx * r.z;
                S[7]  += qy * r.x; S[8]  += qy * r.y; S[9]  += qy * r.z;
                S[10] += qz * r.x; S[11] += qz * r.y; S[12] += qz * r.z;
                idx += 8;
                r = rn;
            }
#pragma unroll
            for (int k = 0; k < NPARA; k++) {
                S[k] += __shfl_xor(S[k], 8, 64);
                S[k] += __shfl_xor(S[k], 16, 64);
                S[k] += __shfl_xor(S[k], 32, 64);
            }
            if (pl == 0) {
#pragma unroll
                for (int k = 0; k < NPARA; k++) stash[wave][w * 16 + k] = S[k];
            }
            // wave-private LDS stash: in-wave ds ordering via lgkmcnt, no barrier

            const int o0 = lane, o1 = lane + 64;
            float hw0[NPARA], hw1[NPARA];
#pragma unroll
            for (int k = 0; k < NPARA; k++) { hw0[k] = 0.0f; hw1[k] = 0.0f; }
#pragma unroll
            for (int w2 = 0; w2 < NWAVE; w2++) {
                const float* Sw = &stash[wave][w2 * 16];
                float4 s0 = *(const float4*)(Sw);
                float4 s1 = *(const float4*)(Sw + 4);
                float4 s2 = *(const float4*)(Sw + 8);
                float  sc = Sw[12];
                float h00 = sHyp[w2 * NORBIT + o0];
                float h01 = sHyp[w2 * NORBIT + o1];
                float h10 = sHyp[(NWAVE + w2) * NORBIT + o0];
                float h11 = sHyp[(NWAVE + w2) * NORBIT + o1];
                float h20 = sHyp[(2 * NWAVE + w2) * NORBIT + o0];
                float h21 = sHyp[(2 * NWAVE + w2) * NORBIT + o1];
                hw0[0]  += s0.x * h00; hw1[0]  += s0.x * h01;
                hw0[1]  += s0.y * h10; hw1[1]  += s0.y * h11;
                hw0[2]  += s0.z * h10; hw1[2]  += s0.z * h11;
                hw0[3]  += s0.w * h10; hw1[3]  += s0.w * h11;
                hw0[4]  += s1.x * h20; hw1[4]  += s1.x * h21;
                hw0[5]  += s1.y * h20; hw1[5]  += s1.y * h21;
                hw0[6]  += s1.z * h20; hw1[6]  += s1.z * h21;
                hw0[7]  += s1.w * h20; hw1[7]  += s1.w * h21;
                hw0[8]  += s2.x * h20; hw1[8]  += s2.x * h21;
                hw0[9]  += s2.y * h20; hw1[9]  += s2.y * h21;
                hw0[10] += s2.z * h20; hw1[10] += s2.z * h21;
                hw0[11] += s2.w * h20; hw1[11] += s2.w * h21;
                hw0[12] += sc   * h20; hw1[12] += sc   * h21;
            }
            float acc0 = 0.0f, acc1 = 0.0f;
#pragma unroll
            for (int k = 0; k < NPARA; k++) {
                acc0 += hw0[k] * hw0[k];
                acc1 += hw1[k] * hw1[k];
            }

            if (mode == 1) {
                out[(size_t)(b * NATOM + ai) * NORBIT + o0] = acc0;
                out[(size_t)(b * NATOM + ai) * NORBIT + o1] = acc1;
                continue;
            }

            // coeff update: full-wave reduction of part[0..7]
            float part[NWAVE];
#pragma unroll
            for (int w2 = 0; w2 < NWAVE; w2++)
                part[w2] = acc0 * sW[o0 * NWAVE + w2] + acc1 * sW[o1 * NWAVE + w2];
#pragma unroll
            for (int m = 1; m <= 4; m <<= 1) {
#pragma unroll
                for (int w2 = 0; w2 < NWAVE; w2++)
                    part[w2] += __shfl_xor(part[w2], m, 64);
            }
            // select part[lane&7], then reduce across octets
            float p0 = (lane & 1) ? part[1] : part[0];
            float p1 = (lane & 1) ? part[3] : part[2];
            float p2 = (lane & 1) ? part[5] : part[4];
            float p3 = (lane & 1) ? part[7] : part[6];
            float q0 = (lane & 2) ? p1 : p0;
            float q1 = (lane & 2) ? p3 : p2;
            float v  = (lane & 4) ? q1 : q0;
            v += __shfl_xor(v, 8, 64);
            v += __shfl_xor(v, 16, 64);
            v += __shfl_xor(v, 32, 64);
            if (lane < NWAVE) {
                int sp = spl[ai];
                cout[ai * NWAVE + lane] =
                    cin[ai * NWAVE + lane] + fast_tanh(v + Eg[sp * NWAVE + lane]);
            }
        }
    };

    pass(cA, cB, sW0, E0, 0);
    __syncthreads();
    pass(cB, cA, sW1, E1, 0);
    __syncthreads();
    pass(cA, nullptr, sW1, E1, 1);
}

extern "C" void kernel_launch(void* const* d_in, const int* in_sizes, int n_in,
                              void* d_out, int out_size, void* d_ws, size_t ws_size,
                              hipStream_t stream) {
    const float* cart    = (const float*)d_in[0];
    const float* shifts  = (const float*)d_in[1];
    const float* rs      = (const float*)d_in[2];
    const float* inta    = (const float*)d_in[3];
    const float* params  = (const float*)d_in[4];
    const float* hyper   = (const float*)d_in[5];
    const float* w0      = (const float*)d_in[6];
    const float* e0      = (const float*)d_in[7];
    const float* w1      = (const float*)d_in[8];
    const float* e1      = (const float*)d_in[9];
    // d_in[10] = numatoms (unused, always NATOM)
    const int* species    = (const int*)d_in[11];
    const int* atom_index = (const int*)d_in[12];
    float* out = (float*)d_out;

    float4* rec = (float4*)d_ws;   // 8 MiB packed pair records

    k_all<<<NB, 1024, 0, stream>>>(atom_index, cart, shifts, species, params,
                                   rs, inta, hyper, w0, e0, w1, e1, rec, out);
}